// Round 19
// baseline (76.103 us; speedup 1.0000x reference)
//
#include <hip/hip_runtime.h>
#include <hip/hip_fp16.h>
#include <math.h>

#define CLIPV 0.03f

struct W9 { float g[9]; };
struct half4 { __half2 a, b; };   // 8 bytes, 2 VGPRs

__device__ __forceinline__ int reflect_idx(int i, int n) {
    if (i < 0) i = -i;
    if (i >= n) i = 2 * n - 2 - i;
    return i;
}

__device__ __forceinline__ float4 h4_to_f4(half4 v) {
    const float2 ab = __half22float2(v.a), cd = __half22float2(v.b);
    float4 r; r.x = ab.x; r.y = ab.y; r.z = cd.x; r.w = cd.y; return r;
}
__device__ __forceinline__ half4 f4_to_h4(float4 v) {
    half4 r; r.a = __floats2half2_rn(v.x, v.y); r.b = __floats2half2_rn(v.z, v.w);
    return r;
}

// ---------------------------------------------------------------------------
// Pass 1: H-conv (x f32 -> t1 fp16) — R9's h_pass verbatim (measured ~9 us).
// One wave = (z-plane, 16-row h-chunk); lane owns 4 consecutive cols.
// 9-deep raw-row f4 ring, depth-2 load pipeline, zero LDS/cross-lane.
// Grid: 1024 blocks x 4 waves = 16 waves/CU. bid&7 = XCD z-band.
// ---------------------------------------------------------------------------
__global__ __launch_bounds__(256) void h_pass(const float* __restrict__ x,
                                              __half* __restrict__ t1, W9 wt) {
    const int bid = blockIdx.x;
    const int xcd = bid & 7;
    const int k   = bid >> 3;              // 0..127
    const int z   = xcd * 32 + (k >> 2);   // XCD-local z band
    const int wv  = threadIdx.x >> 6;
    const int h0  = ((k & 3) * 4 + wv) * 16;   // this wave's 16 output rows
    const int w4  = (threadIdx.x & 63) * 4;

    const float* plane  = x  + (size_t)z * 65536;
    __half*      oplane = t1 + (size_t)z * 65536;

    float4 ring[9];

    float4 cur = *(const float4*)(plane + (size_t)reflect_idx(h0 - 4, 256) * 256 + w4);
    float4 nxt = *(const float4*)(plane + (size_t)reflect_idx(h0 - 3, 256) * 256 + w4);

    #pragma unroll
    for (int i = 0; i < 24; ++i) {
        float4 nn;
        if (i < 22)
            nn = *(const float4*)(plane + (size_t)reflect_idx(h0 - 2 + i, 256) * 256 + w4);

        ring[i % 9] = cur;   // raw row h0-4+i (static index after unroll)

        if (i >= 8) {
            float a0 = 0.f, a1 = 0.f, a2 = 0.f, a3 = 0.f;
            #pragma unroll
            for (int j = 0; j < 9; ++j) {
                const float4 v = ring[(i - 8 + j) % 9];
                a0 = fmaf(wt.g[j], v.x, a0);
                a1 = fmaf(wt.g[j], v.y, a1);
                a2 = fmaf(wt.g[j], v.z, a2);
                a3 = fmaf(wt.g[j], v.w, a3);
            }
            float4 o; o.x = a0; o.y = a1; o.z = a2; o.w = a3;
            *(half4*)(oplane + (size_t)(h0 + i - 8) * 256 + w4) = f4_to_h4(o);
        }

        cur = nxt; nxt = nn;
    }
}

// ---------------------------------------------------------------------------
// Pass 2: W-conv, TRANSPOSED MARCH (t1 fp16 -> t2 fp16).
// The W window becomes the march-axis ring: lane L owns row band+L and
// marches along w. Per iter: ONE half4 load (8B, lane-stride 512B), window
// (w0,w1,w2) = f(c-4),f(c),f(c+4) in registers, 36 FMA, ONE half4 store.
// Zero cross-lane, zero LDS, zero overlap loads — the proven template shape,
// only the addressing is lane-strided (L1/L2 absorb line re-reads).
// Reflect: chunk-uniform register constructs (wL: w0 from w1/w2 at prologue;
// wR: w2 override after the shift at t==14).
// Wave = 64 rows x 64-col chunk; 4 waves/block = one 64-row band, 4 chunks.
// Grid: 1024 blocks (8 xcd x 128: z = xcd*32 + k>>2, band = (k&3)*64).
// ---------------------------------------------------------------------------
__global__ __launch_bounds__(256) void wt_pass(const __half* __restrict__ t1,
                                               __half* __restrict__ t2, W9 wt) {
    const int bid  = blockIdx.x;
    const int xcd  = bid & 7;
    const int k    = bid >> 3;               // 0..127
    const int z    = xcd * 32 + (k >> 2);    // XCD-local z band
    const int band = (k & 3) * 64;
    const int wv   = threadIdx.x >> 6;
    const int c0   = wv * 64;                // this wave's 64-col chunk
    const int L    = threadIdx.x & 63;
    const int r    = band + L;               // this lane's row

    const __half* row  = t1 + (size_t)z * 65536 + (size_t)r * 256;
    __half*       orow = t2 + (size_t)z * 65536 + (size_t)r * 256;

    const bool wL = (c0 == 0), wR = (c0 == 192);   // wave-uniform

    // window: w0=f(c-4), w1=f(c), w2=f(c+4); in-flight: p1=f(c+8), p2=f(c+12)
    float4 w0, w1, w2;
    half4 p1, p2;
    if (wL) {
        w1 = h4_to_f4(*(const half4*)(row + 0));
        w2 = h4_to_f4(*(const half4*)(row + 4));
        // cols -4..-1 reflect to 4,3,2,1
        w0.x = w2.x; w0.y = w1.w; w0.z = w1.z; w0.w = w1.y;
    } else {
        w0 = h4_to_f4(*(const half4*)(row + c0 - 4));
        w1 = h4_to_f4(*(const half4*)(row + c0));
        w2 = h4_to_f4(*(const half4*)(row + c0 + 4));
    }
    p1 = *(const half4*)(row + c0 + 8);      // <= col 200+..: in bounds
    p2 = *(const half4*)(row + c0 + 12);     // <= col 204: in bounds

    #pragma unroll
    for (int t = 0; t < 16; ++t) {
        const int c = c0 + 4 * t;

        // issue the 2-ahead load: f(c0+16+4t), valid through t=12
        half4 pNew;
        if (t <= 12) {
            int cl = c0 + 16 + 4 * t;
            if (wR && cl > 252) cl = 252;    // dummy (slot overridden below)
            pNew = *(const half4*)(row + cl);
        }

        // ---- W-conv: outputs cols c..c+3 from window cols c-4..c+7 ----
        const float sv[12] = {w0.x, w0.y, w0.z, w0.w,
                              w1.x, w1.y, w1.z, w1.w,
                              w2.x, w2.y, w2.z, w2.w};
        float a0 = 0.f, a1 = 0.f, a2 = 0.f, a3 = 0.f;
        #pragma unroll
        for (int j = 0; j < 9; ++j) {
            a0 = fmaf(wt.g[j], sv[j],     a0);
            a1 = fmaf(wt.g[j], sv[j + 1], a1);
            a2 = fmaf(wt.g[j], sv[j + 2], a2);
            a3 = fmaf(wt.g[j], sv[j + 3], a3);
        }
        float4 o; o.x = a0; o.y = a1; o.z = a2; o.w = a3;
        *(half4*)(orow + c) = f4_to_h4(o);

        // ---- shift window / in-flight chain ----
        if (t < 15) {
            w0 = w1; w1 = w2; w2 = h4_to_f4(p1);
            p1 = p2; p2 = pNew;
            if (wR && t == 14) {
                // next window is c=252: w2 must be reflected cols 256..259
                // = {v254, v253, v252, v251}; here w1=f(252), w0=f(248)
                float4 fx; fx.x = w1.z; fx.y = w1.y; fx.z = w1.x; fx.w = w0.w;
                w2 = fx;
            }
        }
    }
}

// ---------------------------------------------------------------------------
// Pass 3: D-conv + clip (t2 fp16 + x f32 -> out f32) — unchanged (measured
// ~14 us, VGPR 60). Thread owns one f4 column, z-chunk 16 (24 iters, amp
// 1.5), 9-deep f32 ring; named depth-2 chains on t2 and x.
// Grid: 1024 blocks x 4 waves; chunks 2*xcd..2*xcd+1 match the writer band.
// ---------------------------------------------------------------------------
__global__ __launch_bounds__(256) void d_clip_pass(const __half* __restrict__ t2,
                                                   const float* __restrict__ x,
                                                   float* __restrict__ out, W9 wt) {
    const int bid   = blockIdx.x;
    const int xcd   = bid & 7;
    const int k     = bid >> 3;                  // 0..127
    const int chunk = xcd * 2 + (k & 1);         // 0..15, XCD-local
    const int tile  = k >> 1;                    // 0..63
    const int z0    = chunk * 16;
    const size_t c4 = (size_t)tile * 256 + threadIdx.x;   // f4-col in plane

    const half4*  t4 = (const half4*)t2;         // plane stride 16384 half4s
    const float4* xp = (const float4*)x;
    float4*       o4 = (float4*)out;

    float4 ring[9];

    half4 cur = t4[(size_t)reflect_idx(z0 - 4, 256) * 16384 + c4];
    half4 nxt = t4[(size_t)reflect_idx(z0 - 3, 256) * 16384 + c4];
    float4 xCur, xNxt;

    #pragma unroll
    for (int i = 0; i < 24; ++i) {
        half4 nn;
        if (i < 22)
            nn = t4[(size_t)reflect_idx(z0 - 2 + i, 256) * 16384 + c4];
        float4 xNew;
        if (i >= 6 && i < 22)   // x plane z0+i-6, consumed at iter i+2
            xNew = xp[(size_t)(z0 + i - 6) * 16384 + c4];

        ring[i % 9] = h4_to_f4(cur);   // plane z0-4+i

        if (i >= 8) {
            const int z = z0 + i - 8;
            float a0 = 0.f, a1 = 0.f, a2 = 0.f, a3 = 0.f;
            #pragma unroll
            for (int j = 0; j < 9; ++j) {
                const float4 v = ring[(i - 8 + j) % 9];
                a0 = fmaf(wt.g[j], v.x, a0);
                a1 = fmaf(wt.g[j], v.y, a1);
                a2 = fmaf(wt.g[j], v.z, a2);
                a3 = fmaf(wt.g[j], v.w, a3);
            }
            const float4 xv = xCur;    // x plane z (loaded at iter i-2)
            float4 r;
            r.x = fmaxf(fminf(xv.x, a0 + CLIPV), a0 - CLIPV);
            r.y = fmaxf(fminf(xv.y, a1 + CLIPV), a1 - CLIPV);
            r.z = fmaxf(fminf(xv.z, a2 + CLIPV), a2 - CLIPV);
            r.w = fmaxf(fminf(xv.w, a3 + CLIPV), a3 - CLIPV);
            o4[(size_t)z * 16384 + c4] = r;
        }

        cur = nxt; nxt = nn;
        xCur = xNxt; xNxt = xNew;
    }
}

extern "C" void kernel_launch(void* const* d_in, const int* in_sizes, int n_in,
                              void* d_out, int out_size, void* d_ws, size_t ws_size,
                              hipStream_t stream) {
    const float* x = (const float*)d_in[0];
    float* out = (float*)d_out;
    __half* t1 = (__half*)d_ws;            // 32 MB
    __half* t2 = t1 + 16777216;            // 32 MB

    // normalized 1-D Gaussian weights (separable form of the reference kernel)
    W9 wt;
    {
        double g[9], s = 0.0;
        const double sigma = 9.0 / 4.0;
        for (int i = 0; i < 9; ++i) {
            double tt = (i - 4.0) / sigma;
            g[i] = exp(-0.5 * tt * tt);
            s += g[i];
        }
        for (int i = 0; i < 9; ++i) wt.g[i] = (float)(g[i] / s);
    }

    h_pass<<<dim3(1024), dim3(256), 0, stream>>>(x, t1, wt);
    wt_pass<<<dim3(1024), dim3(256), 0, stream>>>(t1, t2, wt);
    d_clip_pass<<<dim3(1024), dim3(256), 0, stream>>>(t2, x, out, wt);
}

// Round 20
// 69.571 us; speedup vs baseline: 1.0939x; 1.0939x over previous
//
#include <hip/hip_runtime.h>
#include <hip/hip_fp16.h>
#include <math.h>

#define CLIPV 0.03f

struct W9 { float g[9]; };
struct half4 { __half2 a, b; };   // 8 bytes, 2 VGPRs

__device__ __forceinline__ int reflect_idx(int i, int n) {
    if (i < 0) i = -i;
    if (i >= n) i = 2 * n - 2 - i;
    return i;
}

__device__ __forceinline__ float4 h4_to_f4(half4 v) {
    const float2 ab = __half22float2(v.a), cd = __half22float2(v.b);
    float4 r; r.x = ab.x; r.y = ab.y; r.z = cd.x; r.w = cd.y; return r;
}
__device__ __forceinline__ half4 f4_to_h4(float4 v) {
    half4 r; r.a = __floats2half2_rn(v.x, v.y); r.b = __floats2half2_rn(v.z, v.w);
    return r;
}

// ---------------------------------------------------------------------------
// Pass 1: H-conv (x f32 -> t1 fp16) — R9's h_pass verbatim (measured ~9 us).
// ---------------------------------------------------------------------------
__global__ __launch_bounds__(256) void h_pass(const float* __restrict__ x,
                                              __half* __restrict__ t1, W9 wt) {
    const int bid = blockIdx.x;
    const int xcd = bid & 7;
    const int k   = bid >> 3;              // 0..127
    const int z   = xcd * 32 + (k >> 2);   // XCD-local z band
    const int wv  = threadIdx.x >> 6;
    const int h0  = ((k & 3) * 4 + wv) * 16;   // this wave's 16 output rows
    const int w4  = (threadIdx.x & 63) * 4;

    const float* plane  = x  + (size_t)z * 65536;
    __half*      oplane = t1 + (size_t)z * 65536;

    float4 ring[9];

    float4 cur = *(const float4*)(plane + (size_t)reflect_idx(h0 - 4, 256) * 256 + w4);
    float4 nxt = *(const float4*)(plane + (size_t)reflect_idx(h0 - 3, 256) * 256 + w4);

    #pragma unroll
    for (int i = 0; i < 24; ++i) {
        float4 nn;
        if (i < 22)
            nn = *(const float4*)(plane + (size_t)reflect_idx(h0 - 2 + i, 256) * 256 + w4);

        ring[i % 9] = cur;   // raw row h0-4+i (static index after unroll)

        if (i >= 8) {
            float a0 = 0.f, a1 = 0.f, a2 = 0.f, a3 = 0.f;
            #pragma unroll
            for (int j = 0; j < 9; ++j) {
                const float4 v = ring[(i - 8 + j) % 9];
                a0 = fmaf(wt.g[j], v.x, a0);
                a1 = fmaf(wt.g[j], v.y, a1);
                a2 = fmaf(wt.g[j], v.z, a2);
                a3 = fmaf(wt.g[j], v.w, a3);
            }
            float4 o; o.x = a0; o.y = a1; o.z = a2; o.w = a3;
            *(half4*)(oplane + (size_t)(h0 + i - 8) * 256 + w4) = f4_to_h4(o);
        }

        cur = nxt; nxt = nn;
    }
}

// ---------------------------------------------------------------------------
// Pass 2: W-conv via ONE-SHOT LDS tile (t1 fp16 -> t2 fp16).
// Block = one 64x64 output tile of one plane. Stage 64 rows x 72 cols
// (c0-4..c0+67, reflect baked in) into tile[64][80] (160B row stride) with
// coalesced half4 loads; ONE barrier; each thread computes 4 output half4s
// reading 3x ds_read_b64 (8B-aligned) per output; coalesced half4 stores.
// None of the prior W-killers: no serial march, no overlapping global
// streams, no LDS reuse (one-shot => no R17-style race), no strided global.
// Grid: 4096 blocks (8 xcd x 32 z x 16 tiles) x 256 thr; two generations
// of 8 resident blocks/CU hide the stage latency.
// ---------------------------------------------------------------------------
__global__ __launch_bounds__(256) void w_lds_pass(const __half* __restrict__ t1,
                                                  __half* __restrict__ t2, W9 wt) {
    __shared__ __half tile[64][80];    // cols j=0..71 used; 160B row stride

    const int bid = blockIdx.x;
    const int xcd = bid & 7;
    const int k   = bid >> 3;            // 0..511
    const int z   = xcd * 32 + (k >> 4); // XCD-local z band
    const int t16 = k & 15;
    const int r0  = (t16 >> 2) * 64;     // row band
    const int c0  = (t16 & 3) * 64;      // col chunk
    const int tid = threadIdx.x;

    const __half* plane = t1 + (size_t)z * 65536;

    // ---- stage: 1152 half4 slots (64 rows x 18), idx = tid + 256s ----
    #pragma unroll
    for (int s = 0; s < 5; ++s) {
        const int idx = tid + 256 * s;
        if (idx < 1152) {
            const int row = idx / 18;
            const int j4  = idx - row * 18;
            const int cs  = c0 - 4 + j4 * 4;          // start col of this half4
            const __half* rp = plane + (size_t)(r0 + row) * 256;
            half4 v;
            if (cs >= 0 && cs + 3 <= 255) {
                v = *(const half4*)(rp + cs);         // 8B-aligned (cs mult of 4)
            } else {                                   // only j4=0@c0=0, j4=17@c0=192
                const __half e0 = rp[reflect_idx(cs + 0, 256)];
                const __half e1 = rp[reflect_idx(cs + 1, 256)];
                const __half e2 = rp[reflect_idx(cs + 2, 256)];
                const __half e3 = rp[reflect_idx(cs + 3, 256)];
                v.a = __halves2half2(e0, e1);
                v.b = __halves2half2(e2, e3);
            }
            *(half4*)&tile[row][j4 * 4] = v;
        }
    }
    __syncthreads();

    // ---- compute: 1024 tasks (64 rows x 16 col-groups), 4 per thread ----
    const int m = tid & 15;              // col-group (output cols c0+4m..+3)
    #pragma unroll
    for (int s = 0; s < 4; ++s) {
        const int r = (tid >> 4) + 16 * s;
        // window j = 4m..4m+11  (input cols c0+4m-4 .. c0+4m+7)
        const half4 A = *(const half4*)&tile[r][4 * m];
        const half4 B = *(const half4*)&tile[r][4 * m + 4];
        const half4 C = *(const half4*)&tile[r][4 * m + 8];
        const float4 fa = h4_to_f4(A), fb = h4_to_f4(B), fc = h4_to_f4(C);
        const float sv[12] = {fa.x, fa.y, fa.z, fa.w, fb.x, fb.y, fb.z, fb.w,
                              fc.x, fc.y, fc.z, fc.w};
        float a0 = 0.f, a1 = 0.f, a2 = 0.f, a3 = 0.f;
        #pragma unroll
        for (int j = 0; j < 9; ++j) {
            a0 = fmaf(wt.g[j], sv[j],     a0);
            a1 = fmaf(wt.g[j], sv[j + 1], a1);
            a2 = fmaf(wt.g[j], sv[j + 2], a2);
            a3 = fmaf(wt.g[j], sv[j + 3], a3);
        }
        float4 o; o.x = a0; o.y = a1; o.z = a2; o.w = a3;
        *(half4*)(t2 + (size_t)z * 65536 + (size_t)(r0 + r) * 256 + c0 + 4 * m)
            = f4_to_h4(o);
    }
}

// ---------------------------------------------------------------------------
// Pass 3: D-conv + clip (t2 fp16 + x f32 -> out f32) — unchanged (proven,
// ~12-14 us, VGPR 60). Thread owns one f4 column, z-chunk 16 (24 iters,
// amp 1.5), 9-deep f32 ring; named depth-2 chains on t2 and x.
// ---------------------------------------------------------------------------
__global__ __launch_bounds__(256) void d_clip_pass(const __half* __restrict__ t2,
                                                   const float* __restrict__ x,
                                                   float* __restrict__ out, W9 wt) {
    const int bid   = blockIdx.x;
    const int xcd   = bid & 7;
    const int k     = bid >> 3;                  // 0..127
    const int chunk = xcd * 2 + (k & 1);         // 0..15, XCD-local
    const int tile  = k >> 1;                    // 0..63
    const int z0    = chunk * 16;
    const size_t c4 = (size_t)tile * 256 + threadIdx.x;   // f4-col in plane

    const half4*  t4 = (const half4*)t2;         // plane stride 16384 half4s
    const float4* xp = (const float4*)x;
    float4*       o4 = (float4*)out;

    float4 ring[9];

    half4 cur = t4[(size_t)reflect_idx(z0 - 4, 256) * 16384 + c4];
    half4 nxt = t4[(size_t)reflect_idx(z0 - 3, 256) * 16384 + c4];
    float4 xCur, xNxt;

    #pragma unroll
    for (int i = 0; i < 24; ++i) {
        half4 nn;
        if (i < 22)
            nn = t4[(size_t)reflect_idx(z0 - 2 + i, 256) * 16384 + c4];
        float4 xNew;
        if (i >= 6 && i < 22)   // x plane z0+i-6, consumed at iter i+2
            xNew = xp[(size_t)(z0 + i - 6) * 16384 + c4];

        ring[i % 9] = h4_to_f4(cur);   // plane z0-4+i

        if (i >= 8) {
            const int z = z0 + i - 8;
            float a0 = 0.f, a1 = 0.f, a2 = 0.f, a3 = 0.f;
            #pragma unroll
            for (int j = 0; j < 9; ++j) {
                const float4 v = ring[(i - 8 + j) % 9];
                a0 = fmaf(wt.g[j], v.x, a0);
                a1 = fmaf(wt.g[j], v.y, a1);
                a2 = fmaf(wt.g[j], v.z, a2);
                a3 = fmaf(wt.g[j], v.w, a3);
            }
            const float4 xv = xCur;    // x plane z (loaded at iter i-2)
            float4 r;
            r.x = fmaxf(fminf(xv.x, a0 + CLIPV), a0 - CLIPV);
            r.y = fmaxf(fminf(xv.y, a1 + CLIPV), a1 - CLIPV);
            r.z = fmaxf(fminf(xv.z, a2 + CLIPV), a2 - CLIPV);
            r.w = fmaxf(fminf(xv.w, a3 + CLIPV), a3 - CLIPV);
            o4[(size_t)z * 16384 + c4] = r;
        }

        cur = nxt; nxt = nn;
        xCur = xNxt; xNxt = xNew;
    }
}

extern "C" void kernel_launch(void* const* d_in, const int* in_sizes, int n_in,
                              void* d_out, int out_size, void* d_ws, size_t ws_size,
                              hipStream_t stream) {
    const float* x = (const float*)d_in[0];
    float* out = (float*)d_out;
    __half* t1 = (__half*)d_ws;            // 32 MB
    __half* t2 = t1 + 16777216;            // 32 MB

    // normalized 1-D Gaussian weights (separable form of the reference kernel)
    W9 wt;
    {
        double g[9], s = 0.0;
        const double sigma = 9.0 / 4.0;
        for (int i = 0; i < 9; ++i) {
            double tt = (i - 4.0) / sigma;
            g[i] = exp(-0.5 * tt * tt);
            s += g[i];
        }
        for (int i = 0; i < 9; ++i) wt.g[i] = (float)(g[i] / s);
    }

    h_pass<<<dim3(1024), dim3(256), 0, stream>>>(x, t1, wt);
    w_lds_pass<<<dim3(4096), dim3(256), 0, stream>>>(t1, t2, wt);
    d_clip_pass<<<dim3(1024), dim3(256), 0, stream>>>(t2, x, out, wt);
}

// Round 21
// 53.022 us; speedup vs baseline: 1.4353x; 1.3121x over previous
//
#include <hip/hip_runtime.h>
#include <hip/hip_fp16.h>
#include <math.h>

#define CLIPV 0.03f

// Keep-alive anchor: forces the value to be materialized in VGPRs at this
// program point => the feeding global_load must ISSUE here, not at first use.
// Emits no instruction. (Counters R14/R16: staged loads were being sunk to
// their uses — VGPR 32/60 — serializing one full HBM latency per iteration.)
#define KEEP4(v) asm volatile("" : "+v"((v).x), "+v"((v).y), "+v"((v).z), "+v"((v).w))

struct W9 { float g[9]; };
struct half4 { __half2 a, b; };   // 8 bytes, 2 VGPRs

__device__ __forceinline__ int reflect_idx(int i, int n) {
    if (i < 0) i = -i;
    if (i >= n) i = 2 * n - 2 - i;
    return i;
}

__device__ __forceinline__ float4 h4_to_f4(half4 v) {
    const float2 ab = __half22float2(v.a), cd = __half22float2(v.b);
    float4 r; r.x = ab.x; r.y = ab.y; r.z = cd.x; r.w = cd.y; return r;
}
__device__ __forceinline__ half4 f4_to_h4(float4 v) {
    half4 r; r.a = __floats2half2_rn(v.x, v.y); r.b = __floats2half2_rn(v.z, v.w);
    return r;
}

// ---------------------------------------------------------------------------
// Pass 1: W-conv + H-conv fused (x f32 -> t2 fp16) — R16 structure + KEEP4
// anchors on the staged loads. Per iter: 3 overlapping f4 loads of row i+2
// issued AND PINNED at the top (anchors prevent sinking), W-conv of row i
// from the c* chain (held since iter i-2), 9-ring, H-conv, half4 store.
// Wave = 16 output rows of one z-plane; 24 iters (amp 1.5).
// Grid: 1024 blocks x 4 waves = 16 waves/CU. bid&7 = XCD z-band.
// ---------------------------------------------------------------------------
__global__ __launch_bounds__(256, 4) void wh_pass(const float* __restrict__ x,
                                                  __half* __restrict__ t2, W9 wt) {
    const int bid = blockIdx.x;
    const int xcd = bid & 7;
    const int k   = bid >> 3;                       // 0..127
    const int z   = xcd * 32 + (k >> 2);            // XCD-local z band
    const int wv  = threadIdx.x >> 6;
    const int h0  = ((k & 3) * 4 + wv) * 16;        // 16 output rows
    const int L   = threadIdx.x & 63;
    const int w4  = L * 4;
    const bool l0 = (L == 0), l63 = (L == 63);
    const int offL = l0 ? 1 : (w4 - 4);     // lane 0 loads cols 1..4, reversed
    const int offR = l63 ? 251 : (w4 + 4);  // lane 63 loads 251..254, reversed

    const float* plane  = x  + (size_t)z * 65536;
    __half*      oplane = t2 + (size_t)z * 65536;

    float4 ring[9];

    // named depth-2 staging chains (consume c*, next n*, incoming m*)
    float4 cLf, cCf, cRf, nLf, nCf, nRf;
    {
        const float* r0 = plane + (size_t)reflect_idx(h0 - 4, 256) * 256;
        cLf = *(const float4*)(r0 + offL);
        cCf = *(const float4*)(r0 + w4);
        cRf = *(const float4*)(r0 + offR);
        KEEP4(cLf); KEEP4(cCf); KEEP4(cRf);
        const float* r1 = plane + (size_t)reflect_idx(h0 - 3, 256) * 256;
        nLf = *(const float4*)(r1 + offL);
        nCf = *(const float4*)(r1 + w4);
        nRf = *(const float4*)(r1 + offR);
        KEEP4(nLf); KEEP4(nCf); KEEP4(nRf);
    }

    #pragma unroll
    for (int i = 0; i < 24; ++i) {
        float4 mLf, mCf, mRf;
        if (i < 22) {
            const float* row = plane + (size_t)reflect_idx(h0 - 2 + i, 256) * 256;
            mLf = *(const float4*)(row + offL);
            mCf = *(const float4*)(row + w4);
            mRf = *(const float4*)(row + offR);
            // pin: loads must issue HERE, 1 full iteration before consumption
            KEEP4(mLf); KEEP4(mCf); KEEP4(mRf);
        }

        // ---- W-conv of row h0-4+i (consumes c* chain, in flight 2 iters) ----
        float sv[12];
        sv[0] = l0 ? cLf.w : cLf.x;   // col -4 -> 4
        sv[1] = l0 ? cLf.z : cLf.y;   // col -3 -> 3
        sv[2] = l0 ? cLf.y : cLf.z;   // col -2 -> 2
        sv[3] = l0 ? cLf.x : cLf.w;   // col -1 -> 1
        sv[4] = cCf.x; sv[5] = cCf.y; sv[6] = cCf.z; sv[7] = cCf.w;
        sv[8]  = l63 ? cRf.w : cRf.x; // col 256 -> 254
        sv[9]  = l63 ? cRf.z : cRf.y; // col 257 -> 253
        sv[10] = l63 ? cRf.y : cRf.z; // col 258 -> 252
        sv[11] = l63 ? cRf.x : cRf.w; // col 259 -> 251

        {
            float a0 = 0.f, a1 = 0.f, a2 = 0.f, a3 = 0.f;
            #pragma unroll
            for (int j = 0; j < 9; ++j) {
                a0 = fmaf(wt.g[j], sv[j],     a0);
                a1 = fmaf(wt.g[j], sv[j + 1], a1);
                a2 = fmaf(wt.g[j], sv[j + 2], a2);
                a3 = fmaf(wt.g[j], sv[j + 3], a3);
            }
            float4 wc; wc.x = a0; wc.y = a1; wc.z = a2; wc.w = a3;
            ring[i % 9] = wc;   // static index after full unroll
        }

        // ---- H-conv once ring holds rows hout-4..hout+4 ----
        if (i >= 8) {
            float a0 = 0.f, a1 = 0.f, a2 = 0.f, a3 = 0.f;
            #pragma unroll
            for (int j = 0; j < 9; ++j) {
                const float4 v = ring[(i - 8 + j) % 9];
                a0 = fmaf(wt.g[j], v.x, a0);
                a1 = fmaf(wt.g[j], v.y, a1);
                a2 = fmaf(wt.g[j], v.z, a2);
                a3 = fmaf(wt.g[j], v.w, a3);
            }
            float4 o; o.x = a0; o.y = a1; o.z = a2; o.w = a3;
            *(half4*)(oplane + (size_t)(h0 + i - 8) * 256 + w4) = f4_to_h4(o);
        }

        cLf = nLf; cCf = nCf; cRf = nRf;
        nLf = mLf; nCf = mCf; nRf = mRf;
    }
}

// ---------------------------------------------------------------------------
// Pass 2: D-conv + clip (t2 fp16 + x f32 -> out f32) — unchanged proven
// config (~13 us, VGPR 60). Thread owns one f4 column, z-chunk 16 (24 iters,
// amp 1.5), 9-deep f32 ring; named depth-2 chains on t2 and x.
// Grid: 1024 blocks x 4 waves; chunks 2*xcd..2*xcd+1 match the writer band.
// ---------------------------------------------------------------------------
__global__ __launch_bounds__(256) void d_clip_pass(const __half* __restrict__ t2,
                                                   const float* __restrict__ x,
                                                   float* __restrict__ out, W9 wt) {
    const int bid   = blockIdx.x;
    const int xcd   = bid & 7;
    const int k     = bid >> 3;                  // 0..127
    const int chunk = xcd * 2 + (k & 1);         // 0..15, XCD-local
    const int tile  = k >> 1;                    // 0..63
    const int z0    = chunk * 16;
    const size_t c4 = (size_t)tile * 256 + threadIdx.x;   // f4-col in plane

    const half4*  t4 = (const half4*)t2;         // plane stride 16384 half4s
    const float4* xp = (const float4*)x;
    float4*       o4 = (float4*)out;

    float4 ring[9];

    half4 cur = t4[(size_t)reflect_idx(z0 - 4, 256) * 16384 + c4];
    half4 nxt = t4[(size_t)reflect_idx(z0 - 3, 256) * 16384 + c4];
    float4 xCur, xNxt;

    #pragma unroll
    for (int i = 0; i < 24; ++i) {
        half4 nn;
        if (i < 22)
            nn = t4[(size_t)reflect_idx(z0 - 2 + i, 256) * 16384 + c4];
        float4 xNew;
        if (i >= 6 && i < 22)   // x plane z0+i-6, consumed at iter i+2
            xNew = xp[(size_t)(z0 + i - 6) * 16384 + c4];

        ring[i % 9] = h4_to_f4(cur);   // plane z0-4+i

        if (i >= 8) {
            const int z = z0 + i - 8;
            float a0 = 0.f, a1 = 0.f, a2 = 0.f, a3 = 0.f;
            #pragma unroll
            for (int j = 0; j < 9; ++j) {
                const float4 v = ring[(i - 8 + j) % 9];
                a0 = fmaf(wt.g[j], v.x, a0);
                a1 = fmaf(wt.g[j], v.y, a1);
                a2 = fmaf(wt.g[j], v.z, a2);
                a3 = fmaf(wt.g[j], v.w, a3);
            }
            const float4 xv = xCur;    // x plane z (loaded at iter i-2)
            float4 r;
            r.x = fmaxf(fminf(xv.x, a0 + CLIPV), a0 - CLIPV);
            r.y = fmaxf(fminf(xv.y, a1 + CLIPV), a1 - CLIPV);
            r.z = fmaxf(fminf(xv.z, a2 + CLIPV), a2 - CLIPV);
            r.w = fmaxf(fminf(xv.w, a3 + CLIPV), a3 - CLIPV);
            o4[(size_t)z * 16384 + c4] = r;
        }

        cur = nxt; nxt = nn;
        xCur = xNxt; xNxt = xNew;
    }
}

extern "C" void kernel_launch(void* const* d_in, const int* in_sizes, int n_in,
                              void* d_out, int out_size, void* d_ws, size_t ws_size,
                              hipStream_t stream) {
    const float* x = (const float*)d_in[0];
    float* out = (float*)d_out;
    __half* t2 = (__half*)d_ws;            // 32 MB (single fp16 intermediate)

    // normalized 1-D Gaussian weights (separable form of the reference kernel)
    W9 wt;
    {
        double g[9], s = 0.0;
        const double sigma = 9.0 / 4.0;
        for (int i = 0; i < 9; ++i) {
            double tt = (i - 4.0) / sigma;
            g[i] = exp(-0.5 * tt * tt);
            s += g[i];
        }
        for (int i = 0; i < 9; ++i) wt.g[i] = (float)(g[i] / s);
    }

    wh_pass<<<dim3(1024), dim3(256), 0, stream>>>(x, t2, wt);
    d_clip_pass<<<dim3(1024), dim3(256), 0, stream>>>(t2, x, out, wt);
}

// Round 22
// 51.892 us; speedup vs baseline: 1.4666x; 1.0218x over previous
//
#include <hip/hip_runtime.h>
#include <hip/hip_fp16.h>
#include <math.h>

#define CLIPV 0.03f

struct W9 { float g[9]; };
struct half4 { __half2 a, b; };   // 8 bytes, 2 VGPRs

__device__ __forceinline__ int reflect_idx(int i, int n) {
    if (i < 0) i = -i;
    if (i >= n) i = 2 * n - 2 - i;
    return i;
}

__device__ __forceinline__ float4 h4_to_f4(half4 v) {
    const float2 ab = __half22float2(v.a), cd = __half22float2(v.b);
    float4 r; r.x = ab.x; r.y = ab.y; r.z = cd.x; r.w = cd.y; return r;
}
__device__ __forceinline__ half4 f4_to_h4(float4 v) {
    half4 r; r.a = __floats2half2_rn(v.x, v.y); r.b = __floats2half2_rn(v.z, v.w);
    return r;
}
__device__ __forceinline__ float4 shfl_up1(float4 v) {
    float4 r;
    r.x = __shfl_up(v.x, 1); r.y = __shfl_up(v.y, 1);
    r.z = __shfl_up(v.z, 1); r.w = __shfl_up(v.w, 1);
    return r;
}

// ---------------------------------------------------------------------------
// Pass 1: W+H fused (x f32 -> t2 fp16), HYBRID window sourcing.
// vs R16 (41 us): the left window f4 is no longer a 3rd overlapping load —
// it comes from shfl_up(cC), where cC arrived 2 iterations ago (c-chain), so
// the 4 shfl ops are OFF the load critical path (R6's mistake was shuffling
// both sides = 8 DS ops; here 4). Global streams: 2 (cC @w4, cR @w4+4) =
// 2 KB/wave-iter logical vs 3 KB. Edge reflect: lane 0 from {cR.x, cC.w/z/y}
// (cR.x = col 4); lane 63 keeps the R16 reversed-load cR table.
// Wave = 16 output rows of one z-plane; 24 iters (amp 1.5).
// Grid: 1024 blocks x 4 waves = 16 waves/CU. bid&7 = XCD z-band.
// ---------------------------------------------------------------------------
__global__ __launch_bounds__(256, 4) void wh_pass(const float* __restrict__ x,
                                                  __half* __restrict__ t2, W9 wt) {
    const int bid = blockIdx.x;
    const int xcd = bid & 7;
    const int k   = bid >> 3;                       // 0..127
    const int z   = xcd * 32 + (k >> 2);            // XCD-local z band
    const int wv  = threadIdx.x >> 6;
    const int h0  = ((k & 3) * 4 + wv) * 16;        // 16 output rows
    const int L   = threadIdx.x & 63;
    const int w4  = L * 4;
    const bool l0 = (L == 0), l63 = (L == 63);
    const int offR = l63 ? 251 : (w4 + 4);  // lane 63 loads 251..254, reversed

    const float* plane  = x  + (size_t)z * 65536;
    __half*      oplane = t2 + (size_t)z * 65536;

    float4 ring[9];

    // named depth-2 staging chains (consume c*, next n*, incoming m*)
    float4 cCf, cRf, nCf, nRf;
    {
        const float* r0 = plane + (size_t)reflect_idx(h0 - 4, 256) * 256;
        cCf = *(const float4*)(r0 + w4);
        cRf = *(const float4*)(r0 + offR);
        const float* r1 = plane + (size_t)reflect_idx(h0 - 3, 256) * 256;
        nCf = *(const float4*)(r1 + w4);
        nRf = *(const float4*)(r1 + offR);
    }

    #pragma unroll
    for (int i = 0; i < 24; ++i) {
        float4 mCf, mRf;
        if (i < 22) {
            const float* row = plane + (size_t)reflect_idx(h0 - 2 + i, 256) * 256;
            mCf = *(const float4*)(row + w4);
            mRf = *(const float4*)(row + offR);
        }

        // ---- left window via shuffle of the long-arrived cC ----
        const float4 cLf = shfl_up1(cCf);   // lane L-1's cols w-4..w-1

        // ---- W-conv of row h0-4+i ----
        float sv[12];
        sv[0] = l0 ? cRf.x : cLf.x;   // col -4 -> 4  (lane0: cR = cols 4..7)
        sv[1] = l0 ? cCf.w : cLf.y;   // col -3 -> 3
        sv[2] = l0 ? cCf.z : cLf.z;   // col -2 -> 2
        sv[3] = l0 ? cCf.y : cLf.w;   // col -1 -> 1
        sv[4] = cCf.x; sv[5] = cCf.y; sv[6] = cCf.z; sv[7] = cCf.w;
        sv[8]  = l63 ? cRf.w : cRf.x; // col 256 -> 254 (lane63: cR=251..254 rev)
        sv[9]  = l63 ? cRf.z : cRf.y; // col 257 -> 253
        sv[10] = l63 ? cRf.y : cRf.z; // col 258 -> 252
        sv[11] = l63 ? cRf.x : cRf.w; // col 259 -> 251

        {
            float a0 = 0.f, a1 = 0.f, a2 = 0.f, a3 = 0.f;
            #pragma unroll
            for (int j = 0; j < 9; ++j) {
                a0 = fmaf(wt.g[j], sv[j],     a0);
                a1 = fmaf(wt.g[j], sv[j + 1], a1);
                a2 = fmaf(wt.g[j], sv[j + 2], a2);
                a3 = fmaf(wt.g[j], sv[j + 3], a3);
            }
            float4 wc; wc.x = a0; wc.y = a1; wc.z = a2; wc.w = a3;
            ring[i % 9] = wc;   // static index after full unroll
        }

        // ---- H-conv once ring holds rows hout-4..hout+4 ----
        if (i >= 8) {
            float a0 = 0.f, a1 = 0.f, a2 = 0.f, a3 = 0.f;
            #pragma unroll
            for (int j = 0; j < 9; ++j) {
                const float4 v = ring[(i - 8 + j) % 9];
                a0 = fmaf(wt.g[j], v.x, a0);
                a1 = fmaf(wt.g[j], v.y, a1);
                a2 = fmaf(wt.g[j], v.z, a2);
                a3 = fmaf(wt.g[j], v.w, a3);
            }
            float4 o; o.x = a0; o.y = a1; o.z = a2; o.w = a3;
            *(half4*)(oplane + (size_t)(h0 + i - 8) * 256 + w4) = f4_to_h4(o);
        }

        cCf = nCf; cRf = nRf;
        nCf = mCf; nRf = mRf;
    }
}

// ---------------------------------------------------------------------------
// Pass 2: D-conv + clip (t2 fp16 + x f32 -> out f32) — unchanged proven
// config (~13 us, VGPR 60). Thread owns one f4 column, z-chunk 16 (24 iters,
// amp 1.5), 9-deep f32 ring; named depth-2 chains on t2 and x.
// Grid: 1024 blocks x 4 waves; chunks 2*xcd..2*xcd+1 match the writer band.
// ---------------------------------------------------------------------------
__global__ __launch_bounds__(256) void d_clip_pass(const __half* __restrict__ t2,
                                                   const float* __restrict__ x,
                                                   float* __restrict__ out, W9 wt) {
    const int bid   = blockIdx.x;
    const int xcd   = bid & 7;
    const int k     = bid >> 3;                  // 0..127
    const int chunk = xcd * 2 + (k & 1);         // 0..15, XCD-local
    const int tile  = k >> 1;                    // 0..63
    const int z0    = chunk * 16;
    const size_t c4 = (size_t)tile * 256 + threadIdx.x;   // f4-col in plane

    const half4*  t4 = (const half4*)t2;         // plane stride 16384 half4s
    const float4* xp = (const float4*)x;
    float4*       o4 = (float4*)out;

    float4 ring[9];

    half4 cur = t4[(size_t)reflect_idx(z0 - 4, 256) * 16384 + c4];
    half4 nxt = t4[(size_t)reflect_idx(z0 - 3, 256) * 16384 + c4];
    float4 xCur, xNxt;

    #pragma unroll
    for (int i = 0; i < 24; ++i) {
        half4 nn;
        if (i < 22)
            nn = t4[(size_t)reflect_idx(z0 - 2 + i, 256) * 16384 + c4];
        float4 xNew;
        if (i >= 6 && i < 22)   // x plane z0+i-6, consumed at iter i+2
            xNew = xp[(size_t)(z0 + i - 6) * 16384 + c4];

        ring[i % 9] = h4_to_f4(cur);   // plane z0-4+i

        if (i >= 8) {
            const int z = z0 + i - 8;
            float a0 = 0.f, a1 = 0.f, a2 = 0.f, a3 = 0.f;
            #pragma unroll
            for (int j = 0; j < 9; ++j) {
                const float4 v = ring[(i - 8 + j) % 9];
                a0 = fmaf(wt.g[j], v.x, a0);
                a1 = fmaf(wt.g[j], v.y, a1);
                a2 = fmaf(wt.g[j], v.z, a2);
                a3 = fmaf(wt.g[j], v.w, a3);
            }
            const float4 xv = xCur;    // x plane z (loaded at iter i-2)
            float4 r;
            r.x = fmaxf(fminf(xv.x, a0 + CLIPV), a0 - CLIPV);
            r.y = fmaxf(fminf(xv.y, a1 + CLIPV), a1 - CLIPV);
            r.z = fmaxf(fminf(xv.z, a2 + CLIPV), a2 - CLIPV);
            r.w = fmaxf(fminf(xv.w, a3 + CLIPV), a3 - CLIPV);
            o4[(size_t)z * 16384 + c4] = r;
        }

        cur = nxt; nxt = nn;
        xCur = xNxt; xNxt = xNew;
    }
}

extern "C" void kernel_launch(void* const* d_in, const int* in_sizes, int n_in,
                              void* d_out, int out_size, void* d_ws, size_t ws_size,
                              hipStream_t stream) {
    const float* x = (const float*)d_in[0];
    float* out = (float*)d_out;
    __half* t2 = (__half*)d_ws;            // 32 MB (single fp16 intermediate)

    // normalized 1-D Gaussian weights (separable form of the reference kernel)
    W9 wt;
    {
        double g[9], s = 0.0;
        const double sigma = 9.0 / 4.0;
        for (int i = 0; i < 9; ++i) {
            double tt = (i - 4.0) / sigma;
            g[i] = exp(-0.5 * tt * tt);
            s += g[i];
        }
        for (int i = 0; i < 9; ++i) wt.g[i] = (float)(g[i] / s);
    }

    wh_pass<<<dim3(1024), dim3(256), 0, stream>>>(x, t2, wt);
    d_clip_pass<<<dim3(1024), dim3(256), 0, stream>>>(t2, x, out, wt);
}